// Round 1
// baseline (127.026 us; speedup 1.0000x reference)
//
#include <hip/hip_runtime.h>

#define NRAD 16
#define NCH  5    // radial channels (4 zeta + 1 two-body)
#define NZ   4
#define NMON 35
#define OUTW 144  // 16 + 4*32

__global__ __launch_bounds__(256) void mbp_kernel(
    const float* __restrict__ rij_unit,   // [E,3]
    const float* __restrict__ radial_ij,  // [E,16,5]
    const float* __restrict__ lambda_w,   // [2]
    const float* __restrict__ fact_norm,  // [35]
    const int*   __restrict__ first_atom, // [E] sorted
    float* __restrict__ out,              // [nat,144]
    int E)
{
    const int n    = blockIdx.x;
    const int tid  = threadIdx.x;
    const int lane = tid & 63;
    const int sg   = tid >> 6;      // wave id 0..3
    const int zi   = lane >> 4;     // zeta/channel 0..3
    const int r    = lane & 15;     // radial index

    // segment bounds: [lower_bound(n), lower_bound(n+1))
    int lo = 0, hi = E;
    while (lo < hi) { int mid = (lo + hi) >> 1; if (first_atom[mid] < n) lo = mid + 1; else hi = mid; }
    const int start = lo;
    hi = E;
    while (lo < hi) { int mid = (lo + hi) >> 1; if (first_atom[mid] < n + 1) lo = mid + 1; else hi = mid; }
    const int end = lo;

    float acc[NMON];
    #pragma unroll
    for (int l = 0; l < NMON; ++l) acc[l] = 0.f;
    float acc2 = 0.f;  // two-body channel (zi==0 lanes only)

    for (int e = start + sg; e < end; e += 4) {
        const float x = rij_unit[e * 3 + 0];
        const float y = rij_unit[e * 3 + 1];
        const float z = rij_unit[e * 3 + 2];
        const float rad = radial_ij[(e * NRAD + r) * NCH + zi];
        if (zi == 0) acc2 += radial_ij[(e * NRAD + r) * NCH + 4];

        const float x2 = x * x, x3 = x2 * x, x4 = x2 * x2;
        const float y2 = y * y, y3 = y2 * y, y4 = y2 * y2;
        const float z2 = z * z, z3 = z2 * z, z4 = z2 * z2;
        const float xy = x * y, xz = x * z, yz = y * z;

        // monomials in _make_lxlylz order (s asc, lx asc, ly asc)
        acc[0]  += rad;                       // (0,0,0)
        acc[1]  = fmaf(rad, z,       acc[1]); // (0,0,1)
        acc[2]  = fmaf(rad, y,       acc[2]); // (0,1,0)
        acc[3]  = fmaf(rad, x,       acc[3]); // (1,0,0)
        acc[4]  = fmaf(rad, z2,      acc[4]); // (0,0,2)
        acc[5]  = fmaf(rad, yz,      acc[5]); // (0,1,1)
        acc[6]  = fmaf(rad, y2,      acc[6]); // (0,2,0)
        acc[7]  = fmaf(rad, xz,      acc[7]); // (1,0,1)
        acc[8]  = fmaf(rad, xy,      acc[8]); // (1,1,0)
        acc[9]  = fmaf(rad, x2,      acc[9]); // (2,0,0)
        acc[10] = fmaf(rad, z3,      acc[10]);// (0,0,3)
        acc[11] = fmaf(rad, y * z2,  acc[11]);// (0,1,2)
        acc[12] = fmaf(rad, y2 * z,  acc[12]);// (0,2,1)
        acc[13] = fmaf(rad, y3,      acc[13]);// (0,3,0)
        acc[14] = fmaf(rad, x * z2,  acc[14]);// (1,0,2)
        acc[15] = fmaf(rad, xy * z,  acc[15]);// (1,1,1)
        acc[16] = fmaf(rad, x * y2,  acc[16]);// (1,2,0)
        acc[17] = fmaf(rad, x2 * z,  acc[17]);// (2,0,1)
        acc[18] = fmaf(rad, x2 * y,  acc[18]);// (2,1,0)
        acc[19] = fmaf(rad, x3,      acc[19]);// (3,0,0)
        acc[20] = fmaf(rad, z4,      acc[20]);// (0,0,4)
        acc[21] = fmaf(rad, y * z3,  acc[21]);// (0,1,3)
        acc[22] = fmaf(rad, y2 * z2, acc[22]);// (0,2,2)
        acc[23] = fmaf(rad, y3 * z,  acc[23]);// (0,3,1)
        acc[24] = fmaf(rad, y4,      acc[24]);// (0,4,0)
        acc[25] = fmaf(rad, x * z3,  acc[25]);// (1,0,3)
        acc[26] = fmaf(rad, xy * z2, acc[26]);// (1,1,2)
        acc[27] = fmaf(rad, x * y2 * z, acc[27]); // (1,2,1)
        acc[28] = fmaf(rad, x * y3,  acc[28]);// (1,3,0)
        acc[29] = fmaf(rad, x2 * z2, acc[29]);// (2,0,2)
        acc[30] = fmaf(rad, x2 * yz, acc[30]);// (2,1,1)
        acc[31] = fmaf(rad, x2 * y2, acc[31]);// (2,2,0)
        acc[32] = fmaf(rad, x3 * z,  acc[32]);// (3,0,1)
        acc[33] = fmaf(rad, x3 * y,  acc[33]);// (3,1,0)
        acc[34] = fmaf(rad, x4,      acc[34]);// (4,0,0)
    }

    // cross-wave reduction: layout [mono][tid] -> conflict-free LDS
    __shared__ float red[NMON + 1][256];
    #pragma unroll
    for (int l = 0; l < NMON; ++l) red[l][tid] = acc[l];
    red[NMON][tid] = acc2;
    __syncthreads();

    if (tid < 64) {
        float a[NMON];
        #pragma unroll
        for (int l = 0; l < NMON; ++l)
            a[l] = (red[l][tid] + red[l][tid + 64]) + (red[l][tid + 128] + red[l][tid + 192]);
        const float a2 = (red[NMON][tid] + red[NMON][tid + 64]) +
                         (red[NMON][tid + 128] + red[NMON][tid + 192]);

        const float l0 = lambda_w[0], l1 = lambda_w[1];
        const float p0[5] = {1.f, l0, l0 * l0, l0 * l0 * l0, (l0 * l0) * (l0 * l0)};
        const float p1[5] = {1.f, l1, l1 * l1, l1 * l1 * l1, (l1 * l1) * (l1 * l1)};
        const int lsum_tab[NMON] = {0, 1,1,1, 2,2,2,2,2,2,
                                    3,3,3,3,3,3,3,3,3,3,
                                    4,4,4,4,4,4,4,4,4,4,4,4,4,4,4};
        float s0 = 0.f, s1 = 0.f;
        #pragma unroll
        for (int l = 0; l < NMON; ++l) {
            const float f = fact_norm[l];
            const float v = a[l] * f;
            const float v2 = v * v;
            s0 = fmaf(v2, p0[lsum_tab[l]], s0);
            s1 = fmaf(v2, p1[lsum_tab[l]], s1);
        }
        const float scale = 1.0f / (float)(1 << zi);   // 2^(1-zeta), zeta = zi+1
        float* orow = out + (long)n * OUTW;
        orow[16 + zi * 32 + r * 2 + 0] = s0 * scale;
        orow[16 + zi * 32 + r * 2 + 1] = s1 * scale;
        if (zi == 0) orow[r] = a2;   // two-body radial descriptor
    }
}

extern "C" void kernel_launch(void* const* d_in, const int* in_sizes, int n_in,
                              void* d_out, int out_size, void* d_ws, size_t ws_size,
                              hipStream_t stream) {
    const float* rij_unit   = (const float*)d_in[0];
    const float* radial_ij  = (const float*)d_in[1];
    const float* lambda_w   = (const float*)d_in[2];
    const float* fact_norm  = (const float*)d_in[3];
    const int*   first_atom = (const int*)d_in[4];
    // d_in[5] lxlylz, d_in[6] lxlylz_sum: exponent structure is compile-time
    const int E   = in_sizes[4];
    const int nat = out_size / OUTW;

    mbp_kernel<<<nat, 256, 0, stream>>>(rij_unit, radial_ij, lambda_w, fact_norm,
                                        first_atom, (float*)d_out, E);
}

// Round 2
// 107.681 us; speedup vs baseline: 1.1797x; 1.1797x over previous
//
#include <hip/hip_runtime.h>

#define NRAD 16
#define NCH  5
#define NMON 35
#define OUTW 144   // 16 + 4*32

// ---------------- Kernel A: segment offsets from sorted index ---------------
// seg[n] = first edge e with idx[e] >= n ; seg[nat] = E.
__global__ __launch_bounds__(256) void seg_offsets(
    const int* __restrict__ idx, int* __restrict__ seg, int E, int nat)
{
    int e = blockIdx.x * blockDim.x + threadIdx.x;
    if (e >= E) return;
    if (e == 0) {
        const int b = idx[0];
        for (int n = 0; n <= b; ++n) seg[n] = 0;
    } else {
        const int a = idx[e - 1], b = idx[e];
        for (int n = a + 1; n <= b; ++n) seg[n] = e;
    }
    if (e == E - 1) {
        const int a = idx[E - 1];
        for (int n = a + 1; n <= nat; ++n) seg[n] = E;
    }
}

// ---------------- Kernel B: one wave per atom, no LDS ----------------------
__device__ __forceinline__ void edge_body(
    float x, float y, float z, float rad, float c4,
    float acc[NMON], float& acc2)
{
    const float x2 = x * x, x3 = x2 * x, x4 = x2 * x2;
    const float y2 = y * y, y3 = y2 * y, y4 = y2 * y2;
    const float z2 = z * z, z3 = z2 * z, z4 = z2 * z2;
    const float xy = x * y, xz = x * z, yz = y * z;

    acc2 += c4;
    acc[0]  += rad;
    acc[1]  = fmaf(rad, z,        acc[1]);
    acc[2]  = fmaf(rad, y,        acc[2]);
    acc[3]  = fmaf(rad, x,        acc[3]);
    acc[4]  = fmaf(rad, z2,       acc[4]);
    acc[5]  = fmaf(rad, yz,       acc[5]);
    acc[6]  = fmaf(rad, y2,       acc[6]);
    acc[7]  = fmaf(rad, xz,       acc[7]);
    acc[8]  = fmaf(rad, xy,       acc[8]);
    acc[9]  = fmaf(rad, x2,       acc[9]);
    acc[10] = fmaf(rad, z3,       acc[10]);
    acc[11] = fmaf(rad, y * z2,   acc[11]);
    acc[12] = fmaf(rad, y2 * z,   acc[12]);
    acc[13] = fmaf(rad, y3,       acc[13]);
    acc[14] = fmaf(rad, x * z2,   acc[14]);
    acc[15] = fmaf(rad, xy * z,   acc[15]);
    acc[16] = fmaf(rad, x * y2,   acc[16]);
    acc[17] = fmaf(rad, x2 * z,   acc[17]);
    acc[18] = fmaf(rad, x2 * y,   acc[18]);
    acc[19] = fmaf(rad, x3,       acc[19]);
    acc[20] = fmaf(rad, z4,       acc[20]);
    acc[21] = fmaf(rad, y * z3,   acc[21]);
    acc[22] = fmaf(rad, y2 * z2,  acc[22]);
    acc[23] = fmaf(rad, y3 * z,   acc[23]);
    acc[24] = fmaf(rad, y4,       acc[24]);
    acc[25] = fmaf(rad, x * z3,   acc[25]);
    acc[26] = fmaf(rad, xy * z2,  acc[26]);
    acc[27] = fmaf(rad, x * y2 * z, acc[27]);
    acc[28] = fmaf(rad, x * y3,   acc[28]);
    acc[29] = fmaf(rad, x2 * z2,  acc[29]);
    acc[30] = fmaf(rad, x2 * yz,  acc[30]);
    acc[31] = fmaf(rad, x2 * y2,  acc[31]);
    acc[32] = fmaf(rad, x3 * z,   acc[32]);
    acc[33] = fmaf(rad, x3 * y,   acc[33]);
    acc[34] = fmaf(rad, x4,       acc[34]);
}

__global__ __launch_bounds__(256) void mbp_main(
    const float* __restrict__ rij_unit,
    const float* __restrict__ radial_ij,
    const float* __restrict__ lambda_w,
    const float* __restrict__ fact_norm,
    const int*   __restrict__ seg,
    float* __restrict__ out,
    int nat)
{
    const int wave = threadIdx.x >> 6;
    const int n = blockIdx.x * 4 + wave;     // one wave per atom
    if (n >= nat) return;
    const int lane = threadIdx.x & 63;
    const int zi = lane >> 4;                // zeta channel 0..3
    const int r  = lane & 15;                // radial index

    const int start = seg[n];
    const int end   = seg[n + 1];

    float acc[NMON];
    #pragma unroll
    for (int l = 0; l < NMON; ++l) acc[l] = 0.f;
    float acc2 = 0.f;   // two-body (valid on zi==0 lanes; others harmless)

    const int roff = r * NCH + zi;           // lane's radial offset within edge row
    const int coff = r * NCH + 4;            // two-body channel offset

    int e = start;
    // unroll-by-4: issue all loads for 4 edges before any use
    for (; e + 4 <= end; e += 4) {
        float xs[4], ys[4], zs[4], rd[4], c4[4];
        #pragma unroll
        for (int u = 0; u < 4; ++u) {
            const int ee = e + u;
            xs[u] = rij_unit[ee * 3 + 0];
            ys[u] = rij_unit[ee * 3 + 1];
            zs[u] = rij_unit[ee * 3 + 2];
            rd[u] = radial_ij[ee * (NRAD * NCH) + roff];
            c4[u] = radial_ij[ee * (NRAD * NCH) + coff];
        }
        #pragma unroll
        for (int u = 0; u < 4; ++u)
            edge_body(xs[u], ys[u], zs[u], rd[u], c4[u], acc, acc2);
    }
    for (; e < end; ++e) {
        const float x = rij_unit[e * 3 + 0];
        const float y = rij_unit[e * 3 + 1];
        const float z = rij_unit[e * 3 + 2];
        const float rad = radial_ij[e * (NRAD * NCH) + roff];
        const float c4v = radial_ij[e * (NRAD * NCH) + coff];
        edge_body(x, y, z, rad, c4v, acc, acc2);
    }

    // epilogue: every lane already holds complete sums for its (zi, r)
    const float l0 = lambda_w[0], l1 = lambda_w[1];
    const float p0[5] = {1.f, l0, l0 * l0, l0 * l0 * l0, (l0 * l0) * (l0 * l0)};
    const float p1[5] = {1.f, l1, l1 * l1, l1 * l1 * l1, (l1 * l1) * (l1 * l1)};
    const int lsum_tab[NMON] = {0, 1,1,1, 2,2,2,2,2,2,
                                3,3,3,3,3,3,3,3,3,3,
                                4,4,4,4,4,4,4,4,4,4,4,4,4,4,4};
    float s0 = 0.f, s1 = 0.f;
    #pragma unroll
    for (int l = 0; l < NMON; ++l) {
        const float v = acc[l] * fact_norm[l];
        const float v2 = v * v;
        s0 = fmaf(v2, p0[lsum_tab[l]], s0);
        s1 = fmaf(v2, p1[lsum_tab[l]], s1);
    }
    const float scale = 1.0f / (float)(1 << zi);   // 2^(1-zeta)
    float* orow = out + (long)n * OUTW;
    orow[16 + zi * 32 + r * 2 + 0] = s0 * scale;
    orow[16 + zi * 32 + r * 2 + 1] = s1 * scale;
    if (zi == 0) orow[r] = acc2;
}

extern "C" void kernel_launch(void* const* d_in, const int* in_sizes, int n_in,
                              void* d_out, int out_size, void* d_ws, size_t ws_size,
                              hipStream_t stream) {
    const float* rij_unit   = (const float*)d_in[0];
    const float* radial_ij  = (const float*)d_in[1];
    const float* lambda_w   = (const float*)d_in[2];
    const float* fact_norm  = (const float*)d_in[3];
    const int*   first_atom = (const int*)d_in[4];
    const int E   = in_sizes[4];
    const int nat = out_size / OUTW;

    int* seg = (int*)d_ws;   // nat+1 ints

    seg_offsets<<<(E + 255) / 256, 256, 0, stream>>>(first_atom, seg, E, nat);
    mbp_main<<<(nat + 3) / 4, 256, 0, stream>>>(rij_unit, radial_ij, lambda_w,
                                                fact_norm, seg, (float*)d_out, nat);
}